// Round 3
// baseline (257.766 us; speedup 1.0000x reference)
//
#include <hip/hip_runtime.h>
#include <math.h>

typedef __attribute__((ext_vector_type(8))) short bf16x8;
typedef __attribute__((ext_vector_type(4))) float f32x4;

#define GAT_ALPHA 0.2f
#define NSPLIT 16

static __device__ __forceinline__ unsigned short f2bf(float x) {
    unsigned u = __float_as_uint(x);
    u += 0x7fffu + ((u >> 16) & 1u);   // RNE; inputs are finite & non-NaN
    return (unsigned short)(u >> 16);
}

// ---------------- k_prep: h = input @ W (f32), per-row {rowsum, ss=h.c2, sd=h.c1}
__global__ __launch_bounds__(512)
void k_prep(const float* __restrict__ input, const float* __restrict__ W,
            const float* __restrict__ c1, const float* __restrict__ c2,
            unsigned short* __restrict__ hb, float* __restrict__ ssx,
            float* __restrict__ sd, int N, int Fin, int Fout)
{
    __shared__ float in_lds[4][256];
    __shared__ float red[4][3];
    const int tid = threadIdx.x;
    const int r0 = blockIdx.x * 4;
    for (int idx = tid; idx < 4 * Fin; idx += 512) {
        int r = idx / Fin, c = idx - r * Fin;
        in_lds[r][c] = input[(size_t)(r0 + r) * Fin + c];
    }
    if (tid < 12) ((float*)red)[tid] = 0.f;
    __syncthreads();
    const int y = tid >> 7, f = tid & 127;
    float acc = 0.f;
    for (int k = 0; k < Fin; ++k)
        acc = fmaf(in_lds[y][k], W[(size_t)k * Fout + f], acc);
    const int row = r0 + y;
    hb[(size_t)row * Fout + f] = f2bf(acc);
    float rs = acc, sv = acc * c2[f], dv = acc * c1[f];
    for (int off = 32; off > 0; off >>= 1) {
        rs += __shfl_xor(rs, off);
        sv += __shfl_xor(sv, off);
        dv += __shfl_xor(dv, off);
    }
    if ((tid & 63) == 0) {
        atomicAdd(&red[y][0], rs);
        atomicAdd(&red[y][1], sv);
        atomicAdd(&red[y][2], dv);
    }
    __syncthreads();
    if (f == 0) {
        float rsum = red[y][0];
        ssx[row] = (rsum != 0.f) ? red[y][1] : -1e30f;  // fold j-mask into score
        sd[row]  = red[y][2];
    }
}

// ---------------- k_smax: global masked max of ssx
__global__ __launch_bounds__(1024)
void k_smax(const float* __restrict__ ssx, float* __restrict__ smax, int N)
{
    __shared__ float red[16];
    const int tid = threadIdx.x;
    float m = -3e38f;
    for (int i = tid; i < N; i += 1024) m = fmaxf(m, ssx[i]);
    for (int off = 32; off > 0; off >>= 1) m = fmaxf(m, __shfl_xor(m, off));
    if ((tid & 63) == 0) red[tid >> 6] = m;
    __syncthreads();
    if (tid == 0) {
        float mm = red[0];
        for (int i = 1; i < 16; ++i) mm = fmaxf(mm, red[i]);
        smax[0] = mm;
    }
}

// ---------------- k_transpose: hb [N][Fout] -> ht [Fout][N]
__global__ __launch_bounds__(256)
void k_transpose(const unsigned short* __restrict__ hb, unsigned short* __restrict__ ht,
                 int N, int Fout)
{
    __shared__ unsigned short t[64][65];
    const int bx = blockIdx.x;   // N/64
    const int by = blockIdx.y;   // Fout/64
    const int tid = threadIdx.x;
    for (int i = 0; i < 16; ++i) {
        int idx = i * 256 + tid; int r = idx >> 6, c = idx & 63;
        t[r][c] = hb[(size_t)(bx * 64 + r) * Fout + by * 64 + c];
    }
    __syncthreads();
    for (int i = 0; i < 16; ++i) {
        int idx = i * 256 + tid; int r = idx >> 6, c = idx & 63;
        ht[(size_t)(by * 64 + r) * N + bx * 64 + c] = t[c][r];
    }
}

// ---------------- k_attn: wave-independent flash attention over a j-chunk.
// grid (M/16, NSPLIT), block 64 (1 wave). Each wave: 16 rows x 128 out cols.
// Per iteration: issue B loads FIRST, cover their latency with the exp chain,
// then MFMA. adj is ping-pong prefetched 1 iteration deep (manual unroll-2).
__global__ __launch_bounds__(64, 4)
void k_attn(const int* __restrict__ adj, const unsigned short* __restrict__ ht,
            const float* __restrict__ ssx, const float* __restrict__ sd,
            const float* __restrict__ smaxp, float* __restrict__ outacc,
            float* __restrict__ denom, int N, int M, int Fout)
{
    const int wl = threadIdx.x;
    const int am = wl & 15;            // A-frag row / B-frag col
    const int kg = wl >> 4;            // k-group 0..3
    const int rb = blockIdx.x * 16;
    const int chunk = N / NSPLIT;
    const int j0 = blockIdx.y * chunk;

    const int row = rb + am;           // M % 16 == 0
    const float s = sd[row];
    const float vb = s + smaxp[0];
    const float m = fmaxf(vb, GAT_ALPHA * vb);   // upper bound of valid scores

    const int lane_j = 8 * kg;
    const int* __restrict__ abase = adj + (size_t)row * N + j0 + lane_j;
    const float* __restrict__ sbase = ssx + j0 + lane_j;
    const unsigned short* __restrict__ hb8 = ht + (size_t)am * N + j0 + lane_j;

    f32x4 acc[8];
    #pragma unroll
    for (int c = 0; c < 8; ++c) acc[c] = (f32x4){0.f, 0.f, 0.f, 0.f};
    float dloc = 0.f;

    const int NT = chunk >> 5;         // j-steps of 32

    int4 aA0 = *(const int4*)(abase);
    int4 aA1 = *(const int4*)(abase + 4);
    int4 aB0, aB1;

    auto STEP = [&](int jt, int4& c0, int4& c1, int4& n0, int4& n1) {
        // 1. prefetch next iteration's adj (HBM, 900 cyc away)
        const int noff = (jt + 1 < NT) ? (jt + 1) * 32 : 0;   // uniform s_cselect
        n0 = *(const int4*)(abase + noff);
        n1 = *(const int4*)(abase + noff + 4);
        // 2. issue this iteration's ssx + all 8 B-fragment loads (L2-resident)
        float4 s0 = *(const float4*)(sbase + jt * 32);
        float4 s1 = *(const float4*)(sbase + jt * 32 + 4);
        bf16x8 b0 = *(const bf16x8*)(hb8 + jt * 32);
        bf16x8 b1 = *(const bf16x8*)(hb8 + jt * 32 + (size_t)16 * N);
        bf16x8 b2 = *(const bf16x8*)(hb8 + jt * 32 + (size_t)32 * N);
        bf16x8 b3 = *(const bf16x8*)(hb8 + jt * 32 + (size_t)48 * N);
        bf16x8 b4 = *(const bf16x8*)(hb8 + jt * 32 + (size_t)64 * N);
        bf16x8 b5 = *(const bf16x8*)(hb8 + jt * 32 + (size_t)80 * N);
        bf16x8 b6 = *(const bf16x8*)(hb8 + jt * 32 + (size_t)96 * N);
        bf16x8 b7 = *(const bf16x8*)(hb8 + jt * 32 + (size_t)112 * N);
        // 3. exp/score chain (covers the load latency above)
        bf16x8 af;
        {
            const int*   ai0 = (const int*)&c0;
            const int*   ai1 = (const int*)&c1;
            const float* sf0 = (const float*)&s0;
            const float* sf1 = (const float*)&s1;
            unsigned short* pu = (unsigned short*)&af;
            float d = 0.f;
            #pragma unroll
            for (int i = 0; i < 4; ++i) {
                float v = s + sf0[i];
                float e = fminf(fmaxf(v, GAT_ALPHA * v) - m, 0.f);
                float p = (ai0[i] > 0) ? __expf(e) : 0.f;
                pu[i] = f2bf(p);
                d += p;
            }
            #pragma unroll
            for (int i = 0; i < 4; ++i) {
                float v = s + sf1[i];
                float e = fminf(fmaxf(v, GAT_ALPHA * v) - m, 0.f);
                float p = (ai1[i] > 0) ? __expf(e) : 0.f;
                pu[4 + i] = f2bf(p);
                d += p;
            }
            dloc += d;
        }
        // 4. MFMA consume
        acc[0] = __builtin_amdgcn_mfma_f32_16x16x32_bf16(af, b0, acc[0], 0, 0, 0);
        acc[1] = __builtin_amdgcn_mfma_f32_16x16x32_bf16(af, b1, acc[1], 0, 0, 0);
        acc[2] = __builtin_amdgcn_mfma_f32_16x16x32_bf16(af, b2, acc[2], 0, 0, 0);
        acc[3] = __builtin_amdgcn_mfma_f32_16x16x32_bf16(af, b3, acc[3], 0, 0, 0);
        acc[4] = __builtin_amdgcn_mfma_f32_16x16x32_bf16(af, b4, acc[4], 0, 0, 0);
        acc[5] = __builtin_amdgcn_mfma_f32_16x16x32_bf16(af, b5, acc[5], 0, 0, 0);
        acc[6] = __builtin_amdgcn_mfma_f32_16x16x32_bf16(af, b6, acc[6], 0, 0, 0);
        acc[7] = __builtin_amdgcn_mfma_f32_16x16x32_bf16(af, b7, acc[7], 0, 0, 0);
    };

    for (int jt = 0; jt + 1 < NT; jt += 2) {
        STEP(jt,     aA0, aA1, aB0, aB1);
        STEP(jt + 1, aB0, aB1, aA0, aA1);
    }
    if (NT & 1) STEP(NT - 1, aA0, aA1, aB0, aB1);

    // denominator: reduce over k-groups (lanes sharing am)
    dloc += __shfl_xor(dloc, 16);
    dloc += __shfl_xor(dloc, 32);
    if (kg == 0) atomicAdd(&denom[row], dloc);

    // D layout: col = lane&15, row = (lane>>4)*4 + reg   [measured m89]
    #pragma unroll
    for (int c = 0; c < 8; ++c) {
        #pragma unroll
        for (int reg = 0; reg < 4; ++reg) {
            const int r = rb + kg * 4 + reg;
            atomicAdd(&outacc[(size_t)r * Fout + 16 * c + am], acc[c][reg]);
        }
    }
}

// ---------------- k_norm: out = elu(out / denom[row]) in place
__global__ __launch_bounds__(256)
void k_norm(float* __restrict__ out, const float* __restrict__ denom, int Fout4)
{
    const int idx = blockIdx.x * 256 + threadIdx.x;   // float4 index
    const int row = idx / Fout4;
    float d = denom[row];
    float inv = (d > 0.f) ? 1.f / d : 0.f;
    float4 v = ((const float4*)out)[idx];
    float* vp = (float*)&v;
    #pragma unroll
    for (int i = 0; i < 4; ++i) {
        float x = vp[i] * inv;
        vp[i] = (x > 0.f) ? x : expm1f(x);
    }
    ((float4*)out)[idx] = v;
}

extern "C" void kernel_launch(void* const* d_in, const int* in_sizes, int n_in,
                              void* d_out, int out_size, void* d_ws, size_t ws_size,
                              hipStream_t stream)
{
    const float* input = (const float*)d_in[0];
    const float* W     = (const float*)d_in[1];
    const float* c1    = (const float*)d_in[2];
    const float* c2    = (const float*)d_in[3];
    const int*   adj   = (const int*)d_in[4];

    const int Fout = in_sizes[2];          // c1: [Fout,1]
    const int Fin  = in_sizes[1] / Fout;   // W: [Fin,Fout]
    const int N    = in_sizes[0] / Fin;    // input: [N,Fin]
    const int M    = out_size / Fout;
    float* out = (float*)d_out;

    char* ws = (char*)d_ws;
    unsigned short* hb = (unsigned short*)ws;                              // N*Fout bf16
    unsigned short* ht = (unsigned short*)(ws + (size_t)N * Fout * 2);     // Fout*N bf16
    float* ssx   = (float*)(ws + (size_t)N * Fout * 4);
    float* sd    = ssx + N;
    float* smax  = sd + N;
    float* denom = smax + 1;                                               // M floats

    hipMemsetAsync(out, 0, (size_t)M * Fout * sizeof(float), stream);
    hipMemsetAsync(denom, 0, (size_t)M * sizeof(float), stream);

    k_prep<<<N / 4, 512, 0, stream>>>(input, W, c1, c2, hb, ssx, sd, N, Fin, Fout);
    k_smax<<<1, 1024, 0, stream>>>(ssx, smax, N);
    k_transpose<<<dim3(N / 64, Fout / 64), 256, 0, stream>>>(hb, ht, N, Fout);
    k_attn<<<dim3(M / 16, NSPLIT), 64, 0, stream>>>(adj, ht, ssx, sd, smax, out, denom, N, M, Fout);
    k_norm<<<(M * Fout / 4 + 255) / 256, 256, 0, stream>>>(out, denom, Fout / 4);
}

// Round 4
// 232.659 us; speedup vs baseline: 1.1079x; 1.1079x over previous
//
#include <hip/hip_runtime.h>
#include <math.h>

typedef __attribute__((ext_vector_type(8))) short bf16x8;
typedef __attribute__((ext_vector_type(4))) float f32x4;

#define GAT_ALPHA 0.2f

static __device__ __forceinline__ unsigned short f2bf(float x) {
    unsigned u = __float_as_uint(x);
    u += 0x7fffu + ((u >> 16) & 1u);   // RNE; inputs are finite & non-NaN
    return (unsigned short)(u >> 16);
}

// ---------------- k_prep: h = input @ W (f32), per-row {rowsum, ss=h.c2, sd=h.c1}
__global__ __launch_bounds__(512)
void k_prep(const float* __restrict__ input, const float* __restrict__ W,
            const float* __restrict__ c1, const float* __restrict__ c2,
            unsigned short* __restrict__ hb, float* __restrict__ ssx,
            float* __restrict__ sd, int N, int Fin, int Fout)
{
    __shared__ float in_lds[4][256];
    __shared__ float red[4][3];
    const int tid = threadIdx.x;
    const int r0 = blockIdx.x * 4;
    for (int idx = tid; idx < 4 * Fin; idx += 512) {
        int r = idx / Fin, c = idx - r * Fin;
        in_lds[r][c] = input[(size_t)(r0 + r) * Fin + c];
    }
    if (tid < 12) ((float*)red)[tid] = 0.f;
    __syncthreads();
    const int y = tid >> 7, f = tid & 127;
    float acc = 0.f;
    for (int k = 0; k < Fin; ++k)
        acc = fmaf(in_lds[y][k], W[(size_t)k * Fout + f], acc);
    const int row = r0 + y;
    hb[(size_t)row * Fout + f] = f2bf(acc);
    float rs = acc, sv = acc * c2[f], dv = acc * c1[f];
    for (int off = 32; off > 0; off >>= 1) {
        rs += __shfl_xor(rs, off);
        sv += __shfl_xor(sv, off);
        dv += __shfl_xor(dv, off);
    }
    if ((tid & 63) == 0) {
        atomicAdd(&red[y][0], rs);
        atomicAdd(&red[y][1], sv);
        atomicAdd(&red[y][2], dv);
    }
    __syncthreads();
    if (f == 0) {
        float rsum = red[y][0];
        ssx[row] = (rsum != 0.f) ? red[y][1] : -1e30f;  // fold j-mask into score
        sd[row]  = red[y][2];
    }
}

// ---------------- k_smax: global masked max of ssx
__global__ __launch_bounds__(1024)
void k_smax(const float* __restrict__ ssx, float* __restrict__ smax, int N)
{
    __shared__ float red[16];
    const int tid = threadIdx.x;
    float m = -3e38f;
    for (int i = tid; i < N; i += 1024) m = fmaxf(m, ssx[i]);
    for (int off = 32; off > 0; off >>= 1) m = fmaxf(m, __shfl_xor(m, off));
    if ((tid & 63) == 0) red[tid >> 6] = m;
    __syncthreads();
    if (tid == 0) {
        float mm = red[0];
        for (int i = 1; i < 16; ++i) mm = fmaxf(mm, red[i]);
        smax[0] = mm;
    }
}

// ---------------- k_transpose: hb [N][Fout] -> ht [Fout][N]
__global__ __launch_bounds__(256)
void k_transpose(const unsigned short* __restrict__ hb, unsigned short* __restrict__ ht,
                 int N, int Fout)
{
    __shared__ unsigned short t[64][65];
    const int bx = blockIdx.x;   // N/64
    const int by = blockIdx.y;   // Fout/64
    const int tid = threadIdx.x;
    for (int i = 0; i < 16; ++i) {
        int idx = i * 256 + tid; int r = idx >> 6, c = idx & 63;
        t[r][c] = hb[(size_t)(bx * 64 + r) * Fout + by * 64 + c];
    }
    __syncthreads();
    for (int i = 0; i < 16; ++i) {
        int idx = i * 256 + tid; int r = idx >> 6, c = idx & 63;
        ht[(size_t)(by * 64 + r) * N + bx * 64 + c] = t[c][r];
    }
}

// ---------------- k_attn: 512-thread blocks, 8 free-running waves (in-block
// j-split), zero global atomics. Wave w: rows [rb,rb+16) x all 128 cols,
// j in [w*N/8,(w+1)*N/8). Epilogue: 8-round staggered LDS combine + direct store.
__global__ __launch_bounds__(512, 4)
void k_attn(const int* __restrict__ adj, const unsigned short* __restrict__ ht,
            const float* __restrict__ ssx, const float* __restrict__ sd,
            const float* __restrict__ smaxp, float* __restrict__ out,
            int N, int M, int Fout)
{
    __shared__ float tile[16][128];
    __shared__ float dl[8][16];

    const int tid = threadIdx.x;
    const int w   = tid >> 6;          // wave id = j-chunk
    const int wl  = tid & 63;
    const int am  = wl & 15;           // A row / B col / D col
    const int kg  = wl >> 4;           // k-group 0..3
    const int rb  = blockIdx.x * 16;
    const int chunk = N >> 3;
    const int j0  = w * chunk;

    const int row = rb + am;
    const float s  = sd[row];
    const float vb = s + smaxp[0];
    const float m  = fmaxf(vb, GAT_ALPHA * vb);   // leakyrelu of max bound

    const int* __restrict__ abase = adj + (size_t)row * N + j0 + 8 * kg;
    const float* __restrict__ sbase = ssx + j0 + 8 * kg;
    const unsigned short* __restrict__ hbase = ht + (size_t)am * N + j0 + 8 * kg;
    const size_t cs = (size_t)16 * N;  // c-group row stride in ht

    f32x4 acc[8];
    #pragma unroll
    for (int c = 0; c < 8; ++c) acc[c] = (f32x4){0.f, 0.f, 0.f, 0.f};
    float dloc = 0.f;

    const int NT = chunk >> 5;         // j-steps of 32

    // prologue: adj/ssx for jt=0, bA half for jt=0
    int4 aC0 = *(const int4*)(abase);
    int4 aC1 = *(const int4*)(abase + 4);
    float4 sC0 = *(const float4*)(sbase);
    float4 sC1 = *(const float4*)(sbase + 4);
    bf16x8 bA0 = *(const bf16x8*)(hbase);
    bf16x8 bA1 = *(const bf16x8*)(hbase + cs);
    bf16x8 bA2 = *(const bf16x8*)(hbase + 2 * cs);
    bf16x8 bA3 = *(const bf16x8*)(hbase + 3 * cs);
    int4 aN0, aN1; float4 sN0, sN1;

    auto STEP = [&](int jt, int4& c0, int4& c1, float4& p0, float4& p1,
                    int4& n0, int4& n1, float4& q0, float4& q1) {
        const unsigned short* hj = hbase + jt * 32;
        // 1. second B half for THIS step (covered by exp chain)
        bf16x8 bB0 = *(const bf16x8*)(hj + 4 * cs);
        bf16x8 bB1 = *(const bf16x8*)(hj + 5 * cs);
        bf16x8 bB2 = *(const bf16x8*)(hj + 6 * cs);
        bf16x8 bB3 = *(const bf16x8*)(hj + 7 * cs);
        // 2. next step's ssx (issued BEFORE adj so its vmcnt doesn't drain adj)
        const int nj = (jt + 1 < NT) ? (jt + 1) * 32 : 0;
        q0 = *(const float4*)(sbase + nj);
        q1 = *(const float4*)(sbase + nj + 4);
        // 3. next step's adj (HBM/L3, full iteration to return)
        n0 = *(const int4*)(abase + nj);
        n1 = *(const int4*)(abase + nj + 4);
        // 4. exp/score chain on current values
        bf16x8 af;
        {
            const int*   ai0 = (const int*)&c0;
            const int*   ai1 = (const int*)&c1;
            const float* sf0 = (const float*)&p0;
            const float* sf1 = (const float*)&p1;
            unsigned short* pu = (unsigned short*)&af;
            float d = 0.f;
            #pragma unroll
            for (int i = 0; i < 4; ++i) {
                float v = s + sf0[i];
                float e = fminf(fmaxf(v, GAT_ALPHA * v) - m, 0.f);
                float p = (ai0[i] > 0) ? __expf(e) : 0.f;
                pu[i] = f2bf(p);
                d += p;
            }
            #pragma unroll
            for (int i = 0; i < 4; ++i) {
                float v = s + sf1[i];
                float e = fminf(fmaxf(v, GAT_ALPHA * v) - m, 0.f);
                float p = (ai1[i] > 0) ? __expf(e) : 0.f;
                pu[4 + i] = f2bf(p);
                d += p;
            }
            dloc += d;
        }
        // 5. first MFMA quad consumes bA (loaded last step)
        acc[0] = __builtin_amdgcn_mfma_f32_16x16x32_bf16(af, bA0, acc[0], 0, 0, 0);
        acc[1] = __builtin_amdgcn_mfma_f32_16x16x32_bf16(af, bA1, acc[1], 0, 0, 0);
        acc[2] = __builtin_amdgcn_mfma_f32_16x16x32_bf16(af, bA2, acc[2], 0, 0, 0);
        acc[3] = __builtin_amdgcn_mfma_f32_16x16x32_bf16(af, bA3, acc[3], 0, 0, 0);
        // 6. reload bA for NEXT step (covered by second MFMA quad + next chain)
        const unsigned short* hn = hbase + nj;
        bA0 = *(const bf16x8*)(hn);
        bA1 = *(const bf16x8*)(hn + cs);
        bA2 = *(const bf16x8*)(hn + 2 * cs);
        bA3 = *(const bf16x8*)(hn + 3 * cs);
        // 7. second MFMA quad consumes bB
        acc[4] = __builtin_amdgcn_mfma_f32_16x16x32_bf16(af, bB0, acc[4], 0, 0, 0);
        acc[5] = __builtin_amdgcn_mfma_f32_16x16x32_bf16(af, bB1, acc[5], 0, 0, 0);
        acc[6] = __builtin_amdgcn_mfma_f32_16x16x32_bf16(af, bB2, acc[6], 0, 0, 0);
        acc[7] = __builtin_amdgcn_mfma_f32_16x16x32_bf16(af, bB3, acc[7], 0, 0, 0);
    };

    for (int jt = 0; jt + 1 < NT; jt += 2) {
        STEP(jt,     aC0, aC1, sC0, sC1, aN0, aN1, sN0, sN1);
        STEP(jt + 1, aN0, aN1, sN0, sN1, aC0, aC1, sC0, sC1);
    }
    if (NT & 1) STEP(NT - 1, aC0, aC1, sC0, sC1, aN0, aN1, sN0, sN1);

    // denominator partial for this wave's chunk: reduce over k-groups
    dloc += __shfl_xor(dloc, 16);
    dloc += __shfl_xor(dloc, 32);
    if (kg == 0) dl[w][am] = dloc;

    // staggered accumulation into shared tile: round r, wave w owns c=(w+r)&7
    #pragma unroll
    for (int r = 0; r < 8; ++r) {
        const int c = (w + r) & 7;
        const int col = 16 * c + am;
        if (r == 0) {
            #pragma unroll
            for (int reg = 0; reg < 4; ++reg)
                tile[kg * 4 + reg][col] = acc[c][reg];
        } else {
            #pragma unroll
            for (int reg = 0; reg < 4; ++reg)
                tile[kg * 4 + reg][col] += acc[c][reg];
        }
        __syncthreads();
    }

    // epilogue: normalize + ELU + coalesced store (512 threads x float4)
    {
        const int r  = tid >> 5;
        const int c4 = (tid & 31) * 4;
        float d = 0.f;
        #pragma unroll
        for (int ww = 0; ww < 8; ++ww) d += dl[ww][r];
        const float inv = (d > 0.f) ? 1.f / d : 0.f;
        float4 v = *(const float4*)&tile[r][c4];
        float* vp = (float*)&v;
        #pragma unroll
        for (int i = 0; i < 4; ++i) {
            float x = vp[i] * inv;
            vp[i] = (x > 0.f) ? x : expm1f(x);
        }
        *(float4*)(out + (size_t)(rb + r) * Fout + c4) = v;
    }
}

extern "C" void kernel_launch(void* const* d_in, const int* in_sizes, int n_in,
                              void* d_out, int out_size, void* d_ws, size_t ws_size,
                              hipStream_t stream)
{
    const float* input = (const float*)d_in[0];
    const float* W     = (const float*)d_in[1];
    const float* c1    = (const float*)d_in[2];
    const float* c2    = (const float*)d_in[3];
    const int*   adj   = (const int*)d_in[4];

    const int Fout = in_sizes[2];          // c1: [Fout,1]
    const int Fin  = in_sizes[1] / Fout;   // W: [Fin,Fout]
    const int N    = in_sizes[0] / Fin;    // input: [N,Fin]
    const int M    = out_size / Fout;
    float* out = (float*)d_out;

    char* ws = (char*)d_ws;
    unsigned short* hb = (unsigned short*)ws;                              // N*Fout bf16
    unsigned short* ht = (unsigned short*)(ws + (size_t)N * Fout * 2);     // Fout*N bf16
    float* ssx   = (float*)(ws + (size_t)N * Fout * 4);
    float* sd    = ssx + N;
    float* smax  = sd + N;

    k_prep<<<N / 4, 512, 0, stream>>>(input, W, c1, c2, hb, ssx, sd, N, Fin, Fout);
    k_smax<<<1, 1024, 0, stream>>>(ssx, smax, N);
    k_transpose<<<dim3(N / 64, Fout / 64), 256, 0, stream>>>(hb, ht, N, Fout);
    k_attn<<<M / 16, 512, 0, stream>>>(adj, ht, ssx, sd, smax, out, N, M, Fout);
}

// Round 5
// 227.518 us; speedup vs baseline: 1.1330x; 1.0226x over previous
//
#include <hip/hip_runtime.h>
#include <math.h>

typedef __attribute__((ext_vector_type(8))) short bf16x8;
typedef __attribute__((ext_vector_type(4))) float f32x4;

#define GAT_ALPHA 0.2f

static __device__ __forceinline__ unsigned short f2bf(float x) {
    unsigned u = __float_as_uint(x);
    u += 0x7fffu + ((u >> 16) & 1u);   // RNE; inputs are finite & non-NaN
    return (unsigned short)(u >> 16);
}

// ---------------- k_prep: h = input @ W (f32), per-row {rowsum, ss=h.c2, sd=h.c1}
__global__ __launch_bounds__(512)
void k_prep(const float* __restrict__ input, const float* __restrict__ W,
            const float* __restrict__ c1, const float* __restrict__ c2,
            unsigned short* __restrict__ hb, float* __restrict__ ssx,
            float* __restrict__ sd, int N, int Fin, int Fout)
{
    __shared__ float in_lds[4][256];
    __shared__ float red[4][3];
    const int tid = threadIdx.x;
    const int r0 = blockIdx.x * 4;
    for (int idx = tid; idx < 4 * Fin; idx += 512) {
        int r = idx / Fin, c = idx - r * Fin;
        in_lds[r][c] = input[(size_t)(r0 + r) * Fin + c];
    }
    if (tid < 12) ((float*)red)[tid] = 0.f;
    __syncthreads();
    const int y = tid >> 7, f = tid & 127;
    float acc = 0.f;
    for (int k = 0; k < Fin; ++k)
        acc = fmaf(in_lds[y][k], W[(size_t)k * Fout + f], acc);
    const int row = r0 + y;
    hb[(size_t)row * Fout + f] = f2bf(acc);
    float rs = acc, sv = acc * c2[f], dv = acc * c1[f];
    for (int off = 32; off > 0; off >>= 1) {
        rs += __shfl_xor(rs, off);
        sv += __shfl_xor(sv, off);
        dv += __shfl_xor(dv, off);
    }
    if ((tid & 63) == 0) {
        atomicAdd(&red[y][0], rs);
        atomicAdd(&red[y][1], sv);
        atomicAdd(&red[y][2], dv);
    }
    __syncthreads();
    if (f == 0) {
        float rsum = red[y][0];
        ssx[row] = (rsum != 0.f) ? red[y][1] : -1e30f;  // fold j-mask into score
        sd[row]  = red[y][2];
    }
}

// ---------------- k_smax: global masked max of ssx
__global__ __launch_bounds__(1024)
void k_smax(const float* __restrict__ ssx, float* __restrict__ smax, int N)
{
    __shared__ float red[16];
    const int tid = threadIdx.x;
    float m = -3e38f;
    for (int i = tid; i < N; i += 1024) m = fmaxf(m, ssx[i]);
    for (int off = 32; off > 0; off >>= 1) m = fmaxf(m, __shfl_xor(m, off));
    if ((tid & 63) == 0) red[tid >> 6] = m;
    __syncthreads();
    if (tid == 0) {
        float mm = red[0];
        for (int i = 1; i < 16; ++i) mm = fmaxf(mm, red[i]);
        smax[0] = mm;
    }
}

// ---------------- k_transpose: hb [N][Fout] -> ht [Fout][N]
__global__ __launch_bounds__(256)
void k_transpose(const unsigned short* __restrict__ hb, unsigned short* __restrict__ ht,
                 int N, int Fout)
{
    __shared__ unsigned short t[64][65];
    const int bx = blockIdx.x;   // N/64
    const int by = blockIdx.y;   // Fout/64
    const int tid = threadIdx.x;
    for (int i = 0; i < 16; ++i) {
        int idx = i * 256 + tid; int r = idx >> 6, c = idx & 63;
        t[r][c] = hb[(size_t)(bx * 64 + r) * Fout + by * 64 + c];
    }
    __syncthreads();
    for (int i = 0; i < 16; ++i) {
        int idx = i * 256 + tid; int r = idx >> 6, c = idx & 63;
        ht[(size_t)(by * 64 + r) * N + bx * 64 + c] = t[c][r];
    }
}

// ---------------- k_attn: two-phase. Phase 1: block bitpacks its 16 adj rows
// (coalesced 512KB HBM stream) into a 2N-byte LDS bitmask (bank-swizzled).
// Phase 2: 8 free-running waves (in-block j-split), loop touches only
// L2-class data (ht, ssx) + LDS bits -> runs at issue rate, no HBM latency.
__global__ __launch_bounds__(512, 4)
void k_attn(const int* __restrict__ adj, const unsigned short* __restrict__ ht,
            const float* __restrict__ ssx, const float* __restrict__ sd,
            const float* __restrict__ smaxp, float* __restrict__ out,
            int N, int M, int Fout)
{
    extern __shared__ char smem[];
    unsigned char* __restrict__ bmb = (unsigned char*)smem;        // 2N bytes
    float* __restrict__ tile = (float*)(smem + 2 * (size_t)N);     // 16*128 f32
    float* __restrict__ dl   = tile + 16 * 128;                    // 8*16 f32

    const int tid = threadIdx.x;
    const int w   = tid >> 6;          // wave id = j-chunk
    const int wl  = tid & 63;
    const int am  = wl & 15;           // A row / B col / D col
    const int kg  = wl >> 4;           // k-group 0..3
    const int rb  = blockIdx.x * 16;
    const unsigned nbytes_row = (unsigned)N >> 3;

    // ---- phase 1: bitpack adj[rb..rb+16) into LDS (coalesced, 8 ints/thread/iter)
    {
        const unsigned total = 16u * (unsigned)N;
        for (unsigned f = tid * 8u; f < total; f += 512u * 8u) {
            unsigned rl = f / (unsigned)N;
            unsigned j  = f - rl * (unsigned)N;
            const int* ap = adj + (size_t)(rb + rl) * N + j;
            int4 v0 = *(const int4*)ap;
            int4 v1 = *(const int4*)(ap + 4);
            unsigned b = (unsigned)(v0.x > 0)       | ((unsigned)(v0.y > 0) << 1)
                       | ((unsigned)(v0.z > 0) << 2) | ((unsigned)(v0.w > 0) << 3)
                       | ((unsigned)(v1.x > 0) << 4) | ((unsigned)(v1.y > 0) << 5)
                       | ((unsigned)(v1.z > 0) << 6) | ((unsigned)(v1.w > 0) << 7);
            // swizzled: word index (j>>5) XOR rl spreads rows across banks
            bmb[rl * nbytes_row + ((((j >> 5) ^ rl) << 2) | ((j >> 3) & 3u))] = (unsigned char)b;
        }
    }
    __syncthreads();

    // ---- phase 2 setup
    const int chunk = N >> 3;
    const int j0  = w * chunk;
    const int W0  = j0 >> 5;           // first bitmask word of this wave's chunk
    const int row = rb + am;
    const float s  = sd[row];
    const float vb = s + smaxp[0];
    const float m  = fmaxf(vb, GAT_ALPHA * vb);   // leakyrelu of max valid score

    const float* __restrict__ sbase = ssx + j0 + 8 * kg;
    const unsigned short* __restrict__ hbase = ht + (size_t)am * N + j0 + 8 * kg;
    const size_t cs = (size_t)16 * N;  // c-group row stride in ht
    const unsigned char* __restrict__ bmrow = bmb + am * nbytes_row;

    f32x4 acc[8];
    #pragma unroll
    for (int c = 0; c < 8; ++c) acc[c] = (f32x4){0.f, 0.f, 0.f, 0.f};
    float dloc = 0.f;

    const int NT = chunk >> 5;         // j-steps of 32

    // prologue: ssx + bm word + bA half for jt=0
    float4 sC0 = *(const float4*)(sbase);
    float4 sC1 = *(const float4*)(sbase + 4);
    unsigned bmC = *(const unsigned*)(bmrow + (((unsigned)(W0) ^ (unsigned)am) << 2));
    bf16x8 bA0 = *(const bf16x8*)(hbase);
    bf16x8 bA1 = *(const bf16x8*)(hbase + cs);
    bf16x8 bA2 = *(const bf16x8*)(hbase + 2 * cs);
    bf16x8 bA3 = *(const bf16x8*)(hbase + 3 * cs);
    float4 sN0, sN1; unsigned bmN;

    auto STEP = [&](int jt, float4& p0, float4& p1, unsigned& bmc,
                    float4& q0, float4& q1, unsigned& bmn) {
        const unsigned short* hj = hbase + jt * 32;
        // 1. second B half for THIS step (covered by exp chain)
        bf16x8 bB0 = *(const bf16x8*)(hj + 4 * cs);
        bf16x8 bB1 = *(const bf16x8*)(hj + 5 * cs);
        bf16x8 bB2 = *(const bf16x8*)(hj + 6 * cs);
        bf16x8 bB3 = *(const bf16x8*)(hj + 7 * cs);
        // 2. next step's ssx + bitmask word
        const int nj = (jt + 1 < NT) ? (jt + 1) * 32 : 0;
        q0 = *(const float4*)(sbase + nj);
        q1 = *(const float4*)(sbase + nj + 4);
        bmn = *(const unsigned*)(bmrow + (((unsigned)(W0 + (nj >> 5)) ^ (unsigned)am) << 2));
        // 3. exp/score chain on current values (bits 8kg..8kg+7 of bmc)
        bf16x8 af;
        {
            const unsigned bb = bmc >> (8 * kg);
            const float* sf0 = (const float*)&p0;
            const float* sf1 = (const float*)&p1;
            unsigned short* pu = (unsigned short*)&af;
            float d = 0.f;
            #pragma unroll
            for (int i = 0; i < 4; ++i) {
                float v = s + sf0[i];
                float e = fminf(fmaxf(v, GAT_ALPHA * v) - m, 0.f);
                float p = (bb & (1u << i)) ? __expf(e) : 0.f;
                pu[i] = f2bf(p);
                d += p;
            }
            #pragma unroll
            for (int i = 0; i < 4; ++i) {
                float v = s + sf1[i];
                float e = fminf(fmaxf(v, GAT_ALPHA * v) - m, 0.f);
                float p = (bb & (16u << i)) ? __expf(e) : 0.f;
                pu[4 + i] = f2bf(p);
                d += p;
            }
            dloc += d;
        }
        // 4. first MFMA quad consumes bA (loaded last step)
        acc[0] = __builtin_amdgcn_mfma_f32_16x16x32_bf16(af, bA0, acc[0], 0, 0, 0);
        acc[1] = __builtin_amdgcn_mfma_f32_16x16x32_bf16(af, bA1, acc[1], 0, 0, 0);
        acc[2] = __builtin_amdgcn_mfma_f32_16x16x32_bf16(af, bA2, acc[2], 0, 0, 0);
        acc[3] = __builtin_amdgcn_mfma_f32_16x16x32_bf16(af, bA3, acc[3], 0, 0, 0);
        // 5. reload bA for NEXT step (covered by second MFMA quad + next chain)
        const unsigned short* hn = hbase + nj;
        bA0 = *(const bf16x8*)(hn);
        bA1 = *(const bf16x8*)(hn + cs);
        bA2 = *(const bf16x8*)(hn + 2 * cs);
        bA3 = *(const bf16x8*)(hn + 3 * cs);
        // 6. second MFMA quad consumes bB
        acc[4] = __builtin_amdgcn_mfma_f32_16x16x32_bf16(af, bB0, acc[4], 0, 0, 0);
        acc[5] = __builtin_amdgcn_mfma_f32_16x16x32_bf16(af, bB1, acc[5], 0, 0, 0);
        acc[6] = __builtin_amdgcn_mfma_f32_16x16x32_bf16(af, bB2, acc[6], 0, 0, 0);
        acc[7] = __builtin_amdgcn_mfma_f32_16x16x32_bf16(af, bB3, acc[7], 0, 0, 0);
    };

    for (int jt = 0; jt + 1 < NT; jt += 2) {
        STEP(jt,     sC0, sC1, bmC, sN0, sN1, bmN);
        STEP(jt + 1, sN0, sN1, bmN, sC0, sC1, bmC);
    }
    if (NT & 1) STEP(NT - 1, sC0, sC1, bmC, sN0, sN1, bmN);

    // denominator partial for this wave's chunk: reduce over k-groups
    dloc += __shfl_xor(dloc, 16);
    dloc += __shfl_xor(dloc, 32);
    if (kg == 0) dl[w * 16 + am] = dloc;

    // staggered accumulation into shared tile: round r, wave w owns c=(w+r)&7
    #pragma unroll
    for (int r = 0; r < 8; ++r) {
        const int c = (w + r) & 7;
        const int col = 16 * c + am;
        if (r == 0) {
            #pragma unroll
            for (int reg = 0; reg < 4; ++reg)
                tile[(kg * 4 + reg) * 128 + col] = acc[c][reg];
        } else {
            #pragma unroll
            for (int reg = 0; reg < 4; ++reg)
                tile[(kg * 4 + reg) * 128 + col] += acc[c][reg];
        }
        __syncthreads();
    }

    // epilogue: normalize + ELU + coalesced store (512 threads x float4)
    {
        const int r  = tid >> 5;
        const int c4 = (tid & 31) * 4;
        float d = 0.f;
        #pragma unroll
        for (int ww = 0; ww < 8; ++ww) d += dl[ww * 16 + r];
        const float inv = (d > 0.f) ? 1.f / d : 0.f;
        float4 v = *(const float4*)&tile[r * 128 + c4];
        float* vp = (float*)&v;
        #pragma unroll
        for (int i = 0; i < 4; ++i) {
            float x = vp[i] * inv;
            vp[i] = (x > 0.f) ? x : expm1f(x);
        }
        *(float4*)(out + (size_t)(rb + r) * Fout + c4) = v;
    }
}

extern "C" void kernel_launch(void* const* d_in, const int* in_sizes, int n_in,
                              void* d_out, int out_size, void* d_ws, size_t ws_size,
                              hipStream_t stream)
{
    const float* input = (const float*)d_in[0];
    const float* W     = (const float*)d_in[1];
    const float* c1    = (const float*)d_in[2];
    const float* c2    = (const float*)d_in[3];
    const int*   adj   = (const int*)d_in[4];

    const int Fout = in_sizes[2];          // c1: [Fout,1]
    const int Fin  = in_sizes[1] / Fout;   // W: [Fin,Fout]
    const int N    = in_sizes[0] / Fin;    // input: [N,Fin]
    const int M    = out_size / Fout;
    float* out = (float*)d_out;

    char* ws = (char*)d_ws;
    unsigned short* hb = (unsigned short*)ws;                              // N*Fout bf16
    unsigned short* ht = (unsigned short*)(ws + (size_t)N * Fout * 2);     // Fout*N bf16
    float* ssx   = (float*)(ws + (size_t)N * Fout * 4);
    float* sd    = ssx + N;
    float* smax  = sd + N;

    k_prep<<<N / 4, 512, 0, stream>>>(input, W, c1, c2, hb, ssx, sd, N, Fin, Fout);
    k_smax<<<1, 1024, 0, stream>>>(ssx, smax, N);
    k_transpose<<<dim3(N / 64, Fout / 64), 256, 0, stream>>>(hb, ht, N, Fout);

    const size_t smem_bytes = 2 * (size_t)N + 16 * 128 * 4 + 8 * 16 * 4;
    k_attn<<<M / 16, 512, smem_bytes, stream>>>(adj, ht, ssx, sd, smax, out, N, M, Fout);
}